// Round 5
// baseline (692.187 us; speedup 1.0000x reference)
//
#include <hip/hip_runtime.h>
#include <cstdint>
#include <cstddef>

#pragma clang fp contract(off)

#define N_ANCH 2359296
#define K_PRE  12000
#define K_POST 2000
#define NWORD  188
#define TIE_CAP 65536

typedef unsigned int u32;
typedef unsigned long long u64;

__constant__ float c_anch[9][4] = {
  { -84.f,  -40.f,   99.f,   55.f },
  { -176.f, -88.f,  191.f,  103.f },
  { -360.f, -184.f, 375.f,  199.f },
  { -56.f,  -56.f,   71.f,   71.f },
  { -120.f, -120.f, 135.f,  135.f },
  { -248.f, -248.f, 263.f,  263.f },
  { -36.f,  -80.f,   51.f,   95.f },
  { -80.f,  -168.f,  95.f,  183.f },
  { -168.f, -344.f, 183.f,  359.f },
};

// Replica of XLA:CPU GenerateVF32Exp (Cephes/Eigen expf), UNFUSED mul/add.
__device__ __forceinline__ float pexpf(float xin) {
#pragma clang fp contract(off)
  const float exp_hi = 88.3762626647950f;
  const float exp_lo = -88.3762626647949f;
  const float LOG2EF = 1.44269504088896341f;
  const float C1 = 0.693359375f;
  const float C2 = -2.12194440e-4f;
  const float p0 = 1.9875691500E-4f;
  const float p1 = 1.3981999507E-3f;
  const float p2 = 8.3334519073E-3f;
  const float p3 = 4.1665795894E-2f;
  const float p4 = 1.6666665459E-1f;
  const float p5 = 5.0000001201E-1f;
  float x = fminf(fmaxf(xin, exp_lo), exp_hi);
  float fx = floorf(x * LOG2EF + 0.5f);
  float tmp = C1 * fx;
  float z = C2 * fx;
  x = x - tmp;
  x = x - z;
  z = x * x;
  float y = x * p0 + p1;
  y = y * x + p2;
  y = y * x + p3;
  y = y * x + p4;
  y = y * x + p5;
  y = y * z + x;
  y = 1.0f + y;
  int n = (int)fx;
  u32 e = ((u32)(n + 127)) << 23;
  return y * __uint_as_float(e);
}

__device__ __forceinline__ void decode_box(const float* __restrict__ bbox, int aidx,
                                           float4* ob, float* oarea, bool* okeep) {
#pragma clang fp contract(off)
  int pos = aidx / 9;
  int a = aidx - pos * 9;
  int w = pos & 511;
  int h = pos >> 9;
  float shx = (float)(w * 8);
  float shy = (float)(h * 8);
  float ax1 = c_anch[a][0] + shx;
  float ay1 = c_anch[a][1] + shy;
  float ax2 = c_anch[a][2] + shx;
  float ay2 = c_anch[a][3] + shy;
  float aw = (ax2 - ax1) + 1.0f;
  float ah = (ay2 - ay1) + 1.0f;
  float acx = ax1 + 0.5f * aw;
  float acy = ay1 + 0.5f * ah;
  const float* d = bbox + (size_t)pos * 36 + (size_t)a * 4;
  float dx = d[0], dy = d[1], dw = d[2], dh = d[3];
  float pcx = dx * aw + acx;
  float pcy = dy * ah + acy;
  float pw = pexpf(dw) * aw;
  float ph = pexpf(dh) * ah;
  float x1 = pcx - 0.5f * pw;
  float y1 = pcy - 0.5f * ph;
  float x2 = pcx + 0.5f * pw;
  float y2 = pcy + 0.5f * ph;
  x1 = fminf(fmaxf(x1, 0.0f), 4095.0f);
  y1 = fminf(fmaxf(y1, 0.0f), 4095.0f);
  x2 = fminf(fmaxf(x2, 0.0f), 4095.0f);
  y2 = fminf(fmaxf(y2, 0.0f), 4095.0f);
  *ob = make_float4(x1, y1, x2, y2);
  float ww = (x2 - x1) + 1.0f;
  float hh = (y2 - y1) + 1.0f;
  *oarea = ww * hh;
  *okeep = (ww >= 16.0f) && (hh >= 16.0f);
}

// Stage A (init of ctl/hist fused into block 0).
__global__ void k_scores(const float* __restrict__ cls, const float* __restrict__ bbox,
                         u32* __restrict__ keys, u32* __restrict__ ctl,
                         u32* __restrict__ hist) {
#pragma clang fp contract(off)
  int t = blockIdx.x * blockDim.x + threadIdx.x;
  if (blockIdx.x == 0) {
    if (threadIdx.x < 16) ctl[threadIdx.x] = (threadIdx.x == 1) ? (u32)K_PRE : 0u;
    hist[threadIdx.x] = 0u;
  }
  if (t >= N_ANCH) return;
  int pos = t / 9;
  int a = t - pos * 9;
  float s0 = cls[(size_t)pos * 18 + a];
  float s1 = cls[(size_t)pos * 18 + 9 + a];
  float m = fmaxf(s0, s1);
  float e0 = pexpf(s0 - m);
  float e1 = pexpf(s1 - m);
  float p = e1 / (e0 + e1);
  float4 box; float area; bool km;
  decode_box(bbox, t, &box, &area, &km);
  keys[t] = km ? (__float_as_uint(p) | 0x80000000u) : 0u;
}

// Histogram pass + fused last-block scan (device-scope last-block pattern).
__global__ void k_histscan(const u32* __restrict__ keys, u32* __restrict__ ctl,
                           u32* __restrict__ hist, int shift, int pass) {
  __shared__ u32 lh[256];
  __shared__ u32 s_last;
  int t = threadIdx.x;
  lh[t] = 0u;
  __syncthreads();
  u32 prefix = ctl[0];
  u32 msk = (shift == 24) ? 0u : (0xFFFFFFFFu << (shift + 8));
  int stride = gridDim.x * blockDim.x;
  for (int i = blockIdx.x * blockDim.x + t; i < N_ANCH; i += stride) {
    u32 k = keys[i];
    if ((k & msk) == prefix) atomicAdd(&lh[(k >> shift) & 0xFFu], 1u);
  }
  __syncthreads();
  if (lh[t]) atomicAdd(&hist[t], lh[t]);
  __syncthreads();
  if (t == 0) {
    __threadfence();
    u32 old = atomicAdd(&ctl[8 + pass], 1u);
    s_last = (old == gridDim.x - 1) ? 1u : 0u;
  }
  __syncthreads();
  if (!s_last) return;
  __threadfence();
  __shared__ u32 sh[256];
  __shared__ u32 horig[256];
  __shared__ int s_d;
  u32 h = atomicAdd(&hist[t], 0u);   // coherent read (bypass stale L1)
  sh[t] = h; horig[t] = h;
  if (t == 0) s_d = 0;
  u32 krem = ctl[1];
  __syncthreads();
  u32 v = h;
  for (int off = 1; off < 256; off <<= 1) {
    u32 add = (t + off < 256) ? sh[t + off] : 0u;
    __syncthreads();
    v += add;
    sh[t] = v;
    __syncthreads();
  }
  if (sh[t] >= krem) atomicMax(&s_d, t);
  __syncthreads();
  if (t == 0) {
    int d = s_d;
    u32 cum = sh[d] - horig[d];
    ctl[0] |= ((u32)d) << shift;
    ctl[1] = krem - cum;
    if (shift == 0) { ctl[2] = ctl[0]; ctl[3] = ctl[1]; }
  }
  hist[t] = 0u;
}

// Collect winners; comps built inline (k_build folded in).
__global__ void k_collect(const u32* __restrict__ keys, u32* __restrict__ ctl,
                          int* __restrict__ sel, int* __restrict__ tie,
                          u64* __restrict__ comps) {
  u32 kstar = ctl[2];
  int stride = gridDim.x * blockDim.x;
  for (int i = blockIdx.x * blockDim.x + threadIdx.x; i < N_ANCH; i += stride) {
    u32 k = keys[i];
    if (k > kstar) {
      u32 p = atomicAdd(&ctl[4], 1u);
      sel[p] = i;
      comps[p] = ((u64)k << 32) | (u64)(0xFFFFFFFFu - (u32)i);
    } else if (k == kstar) {
      u32 p = atomicAdd(&ctl[5], 1u);
      if (p < TIE_CAP) tie[p] = i;
    }
  }
}

__global__ void k_tiepick(const u32* __restrict__ ctl, const int* __restrict__ tie,
                          int* __restrict__ sel, u64* __restrict__ comps) {
  u32 T = ctl[5]; if (T > TIE_CAP) T = TIE_CAP;
  if (T > 8192u) T = 8192u;
  u32 need = ctl[3];
  u32 base = ctl[4];
  u32 kstar = ctl[2];
  for (u32 t = threadIdx.x; t < T; t += blockDim.x) {
    int v = tie[t];
    u32 r = 0;
    for (u32 u = 0; u < T; ++u) r += (tie[u] < v) ? 1u : 0u;
    if (r < need) {
      sel[base + r] = v;
      comps[base + r] = ((u64)kstar << 32) | (u64)(0xFFFFFFFFu - (u32)v);
    }
  }
}

// Rank sort: one wave per 8 candidates; coalesced L2-resident j-scan.
__global__ void k_rankdec(const u64* __restrict__ comps, const int* __restrict__ sel,
                          const float* __restrict__ bbox,
                          float4* __restrict__ props, float* __restrict__ areas) {
  int lane = threadIdx.x & 63;
  int wave = threadIdx.x >> 6;
  int base = (blockIdx.x * 4 + wave) * 8;
  u64 c0 = comps[base + 0], c1 = comps[base + 1], c2 = comps[base + 2], c3 = comps[base + 3];
  u64 c4 = comps[base + 4], c5 = comps[base + 5], c6 = comps[base + 6], c7 = comps[base + 7];
  int n0 = 0, n1 = 0, n2 = 0, n3 = 0, n4 = 0, n5 = 0, n6 = 0, n7 = 0;
#pragma unroll 4
  for (int j = lane; j < K_PRE; j += 64) {
    u64 v = comps[j];
    n0 += (v > c0); n1 += (v > c1); n2 += (v > c2); n3 += (v > c3);
    n4 += (v > c4); n5 += (v > c5); n6 += (v > c6); n7 += (v > c7);
  }
  for (int off = 32; off; off >>= 1) {
    n0 += __shfl_xor(n0, off); n1 += __shfl_xor(n1, off);
    n2 += __shfl_xor(n2, off); n3 += __shfl_xor(n3, off);
    n4 += __shfl_xor(n4, off); n5 += __shfl_xor(n5, off);
    n6 += __shfl_xor(n6, off); n7 += __shfl_xor(n7, off);
  }
  int rk = n0;
  rk = (lane == 1) ? n1 : rk; rk = (lane == 2) ? n2 : rk;
  rk = (lane == 3) ? n3 : rk; rk = (lane == 4) ? n4 : rk;
  rk = (lane == 5) ? n5 : rk; rk = (lane == 6) ? n6 : rk;
  rk = (lane == 7) ? n7 : rk;
  if (lane < 8) {
    float4 box; float area; bool km;
    decode_box(bbox, sel[base + lane], &box, &area, &km);
    props[rk] = box;
    areas[rk] = area;
  }
}

// FULL IoU bitmask (both triangles): k_nms's transposed spec reads need
// symmetric blocks (IoU is symmetric, so block(y,x) = block(x,y)^T exists).
__global__ void k_mask(const float4* __restrict__ props, const float* __restrict__ areas,
                       u64* __restrict__ mask) {
#pragma clang fp contract(off)
  __shared__ float4 bj[64];
  __shared__ float aj[64];
  int wj = blockIdx.y;
  int j0 = wj * 64;
  bj[threadIdx.x] = props[j0 + threadIdx.x];
  aj[threadIdx.x] = areas[j0 + threadIdx.x];
  __syncthreads();
  int i = blockIdx.x * 64 + threadIdx.x;
  float4 bi = props[i];
  float ai = areas[i];
  u64 bits = 0;
  for (int jj = 0; jj < 64; ++jj) {
    int j = j0 + jj;
    float4 bb = bj[jj];
    float xx1 = fmaxf(bi.x, bb.x);
    float yy1 = fmaxf(bi.y, bb.y);
    float xx2 = fminf(bi.z, bb.z);
    float yy2 = fminf(bi.w, bb.w);
    float w = fmaxf(0.0f, (xx2 - xx1) + 1.0f);
    float h = fmaxf(0.0f, (yy2 - yy1) + 1.0f);
    float inter = w * h;
    float iou = inter / ((ai + aj[jj]) - inter);
    if ((iou > 0.7f) && (j < K_PRE)) bits |= (1ull << jj);
  }
  mask[(size_t)i * NWORD + wj] = bits;
}

// Raw barrier WITHOUT vmcnt drain: LDS ordering only; global prefetches stay
// in flight across chunks (the __syncthreads vmcnt(0) drain was the R4 stall).
#define NMS_BAR() asm volatile("s_waitcnt lgkmcnt(0)\n\ts_barrier" ::: "memory")

#define FLD(dst, q) dst = mask[(size_t)kptr[(q) < kkI ? (q) : mI] * NWORD + lwI];

// Blocked greedy NMS v5: single barrier per chunk; transposed-spec ballots.
//  - IoU symmetry: suppression of chunk-W lanes by keeps(a) = ballot over lanes
//    of (row(64W+lane) word a) & km(a) — one ballot, no shfl reduce.
//  - wave k (0..3) at chunk c combines keeps(c-k) -> word c+1 (spec preloaded
//    one chunk ahead). wave0 does its own +1 combine right after the decision.
//  - far path (keeps(a) -> words >= a+5): 16 NAMED u64 prefetch regs x2 parity
//    buffers (no arrays -> no scratch), issue at chunk a+2, consume at a+3.
__global__ void __launch_bounds__(256) k_nms(const u64* __restrict__ mask,
                                             const float4* __restrict__ props,
                                             float* __restrict__ out) {
  __shared__ u64 rem[NWORD];
  __shared__ int keepb[K_POST];
  __shared__ int kept[4][64];
  __shared__ int s_kk[4];
  __shared__ u64 s_km[4];
  __shared__ int s_brk[2];
  __shared__ int s_nk;
  int tid = threadIdx.x;
  int lane = tid & 63;
  int wave = tid >> 6;
  for (int w = tid; w < NWORD; w += 256) {
    int base = w * 64;
    u64 v;
    if (base + 64 <= K_PRE) v = 0ull;
    else if (base >= K_PRE) v = ~0ull;
    else v = (~0ull) << (K_PRE - base);
    rem[w] = v;
  }
  if (tid < 4) { s_kk[tid] = 0; s_km[tid] = 0ull; }
  if (tid == 0) { s_nk = 0; s_brk[0] = 0; s_brk[1] = 0; }
  __syncthreads();

  u64 diagA = 0, diagB = 0;
  u64 specA = 0, specB = 0;
  u64 a0=0,a1=0,a2=0,a3=0,a4=0,a5=0,a6=0,a7=0,a8=0,a9=0,a10=0,a11=0,a12=0,a13=0,a14=0,a15=0;
  u64 b0=0,b1=0,b2=0,b3=0,b4=0,b5=0,b6=0,b7=0,b8=0,b9=0,b10=0,b11=0,b12=0,b13=0,b14=0,b15=0;

  if (wave == 0) {
    diagA = mask[(size_t)lane * NWORD + 0];               // rows 0..63, word 0
    specA = mask[(size_t)(64 + lane) * NWORD + 0];        // rows 64..127, word 0
  }
  int nk = 0;   // wave0 running keep count (register)

  for (int c = 0; c < NWORD; ++c) {
    if (s_brk[c & 1]) break;
    if (wave == 0) {
      // preloads for chunk c+1
      if (c + 1 < NWORD)
        diagB = mask[(size_t)((c + 1) * 64 + lane) * NWORD + (c + 1)];
      specB = (c + 2 < NWORD)
            ? mask[(size_t)((c + 2) * 64 + lane) * NWORD + (c + 1)] : 0ull;
      // decision for chunk c
      u64 w = ~rem[c];
      u64 myrow = diagA;
      int kk = 0;
      u64 km = 0;
      while (w != 0ull && nk < K_POST) {
        int j = (int)__builtin_ctzll(w);
        if (lane == 0) { keepb[nk] = (c << 6) | j; kept[c & 3][kk] = (c << 6) | j; }
        km |= (1ull << j);
        nk++; kk++;
        u64 sup = __ballot((int)((myrow >> j) & 1ull));
        w &= ~sup;
        w &= ~(1ull << j);
      }
      // combine keeps(c) -> word c+1 (specA = rows 64(c+1)+lane, word c)
      if (c + 1 < NWORD) {
        u64 v = __ballot((int)((specA & km) != 0ull));
        if (lane == 0 && v) atomicOr(&rem[c + 1], v);
      }
      if (lane == 0) {
        s_kk[c & 3] = kk;
        s_km[c & 3] = km;
        s_nk = nk;
        s_brk[(c + 1) & 1] = (nk >= K_POST) ? 1 : 0;
      }
      diagA = diagB; specA = specB;
    } else {
      // preload spec for chunk c+1 (wave k combines keeps(c+1-k) -> word c+2)
      specB = (c + 2 < NWORD && c + 1 - wave >= 0)
            ? mask[(size_t)((c + 2) * 64 + lane) * NWORD + (c + 1 - wave)] : 0ull;
      // spec combine: keeps(c-wave) -> word c+1
      if (c - wave >= 0 && c + 1 < NWORD) {
        u64 km = s_km[(c - wave) & 3];
        u64 v = __ballot((int)((specA & km) != 0ull));
        if (lane == 0 && v) atomicOr(&rem[c + 1], v);
      }
      specA = specB;
      int ft = tid - 64;
      // far consume: keeps(c-3) -> word c+2+ft (issued at chunk c-1)
      int lwC = c + 2 + ft;
      if (c >= 3 && lwC < NWORD) {
        int kkC = s_kk[(c - 3) & 3];
        if (kkC > 0) {
          u64 v;
          if (c & 1) v = a0|a1|a2|a3|a4|a5|a6|a7|a8|a9|a10|a11|a12|a13|a14|a15;
          else       v = b0|b1|b2|b3|b4|b5|b6|b7|b8|b9|b10|b11|b12|b13|b14|b15;
          if (kkC > 16) {
            const int* kcp = &kept[(c - 3) & 3][0];
            for (int q0 = 16; q0 < kkC; q0 += 8) {
#pragma unroll
              for (int q = 0; q < 8; ++q) {
                int qq = q0 + q;
                v |= mask[(size_t)kcp[qq < kkC ? qq : kkC - 1] * NWORD + lwC];
              }
            }
          }
          if (v) atomicOr(&rem[lwC], v);
        }
      }
      // far issue: keeps(c-2) -> word c+3+ft (consumed at chunk c+1)
      int lwI = c + 3 + ft;
      if (c >= 2 && lwI < NWORD) {
        int kkI = s_kk[(c - 2) & 3];
        if (kkI > 0) {
          const int* kptr = &kept[(c - 2) & 3][0];
          int mI = kkI - 1;
          if ((c & 1) == 0) {
            FLD(a0,0) FLD(a1,1) FLD(a2,2) FLD(a3,3) FLD(a4,4) FLD(a5,5) FLD(a6,6) FLD(a7,7)
            FLD(a8,8) FLD(a9,9) FLD(a10,10) FLD(a11,11) FLD(a12,12) FLD(a13,13) FLD(a14,14) FLD(a15,15)
          } else {
            FLD(b0,0) FLD(b1,1) FLD(b2,2) FLD(b3,3) FLD(b4,4) FLD(b5,5) FLD(b6,6) FLD(b7,7)
            FLD(b8,8) FLD(b9,9) FLD(b10,10) FLD(b11,11) FLD(b12,12) FLD(b13,13) FLD(b14,14) FLD(b15,15)
          }
        }
      }
    }
    NMS_BAR();
  }
  NMS_BAR();
  int fnk = s_nk;
  for (int t = tid; t < K_POST; t += 256) {
    int kidx = (t < fnk) ? keepb[t] : 0;   // exhausted: argmax over -inf -> 0
    float4 b = props[kidx];
    out[t * 5 + 0] = 0.0f;
    out[t * 5 + 1] = b.x;
    out[t * 5 + 2] = b.y;
    out[t * 5 + 3] = b.z;
    out[t * 5 + 4] = b.w;
  }
}

extern "C" void kernel_launch(void* const* d_in, const int* in_sizes, int n_in,
                              void* d_out, int out_size, void* d_ws, size_t ws_size,
                              hipStream_t stream) {
  const float* cls  = (const float*)d_in[0];
  const float* bbox = (const float*)d_in[1];
  float* out = (float*)d_out;
  char* ws = (char*)d_ws;

  u64* mask    = (u64*)ws;                    // [0, 18096128) u64[12032*188]
  u32* keys    = (u32*)ws;                    // [0, 9437184) overlays mask (dead before k_mask)
  u32* ctl     = (u32*)(ws + 9437184);
  u32* hist    = (u32*)(ws + 9437248);
  int* sel     = (int*)(ws + 9438464);
  int* tie     = (int*)(ws + 9486592);
  u64* comps   = (u64*)(ws + 18096128);
  float4* props= (float4*)(ws + 18240512);
  float* areas = (float*)(ws + 18433024);

  k_scores<<<dim3((N_ANCH + 255) / 256), dim3(256), 0, stream>>>(cls, bbox, keys, ctl, hist);
  const int shifts[4] = {24, 16, 8, 0};
  for (int s = 0; s < 4; ++s)
    k_histscan<<<dim3(1024), dim3(256), 0, stream>>>(keys, ctl, hist, shifts[s], s);
  k_collect<<<dim3(1024), dim3(256), 0, stream>>>(keys, ctl, sel, tie, comps);
  k_tiepick<<<dim3(1), dim3(256), 0, stream>>>(ctl, tie, sel, comps);
  k_rankdec<<<dim3(375), dim3(256), 0, stream>>>(comps, sel, bbox, props, areas);
  k_mask<<<dim3(188, 188), dim3(64), 0, stream>>>(props, areas, mask);
  k_nms<<<dim3(1), dim3(256), 0, stream>>>(mask, props, out);
}

// Round 6
// 372.925 us; speedup vs baseline: 1.8561x; 1.8561x over previous
//
#include <hip/hip_runtime.h>
#include <cstdint>
#include <cstddef>

#pragma clang fp contract(off)

#define N_ANCH 2359296
#define K_PRE  12000
#define K_POST 2000
#define NWORD  188
#define TIE_CAP 65536

typedef unsigned int u32;
typedef unsigned long long u64;

__constant__ float c_anch[9][4] = {
  { -84.f,  -40.f,   99.f,   55.f },
  { -176.f, -88.f,  191.f,  103.f },
  { -360.f, -184.f, 375.f,  199.f },
  { -56.f,  -56.f,   71.f,   71.f },
  { -120.f, -120.f, 135.f,  135.f },
  { -248.f, -248.f, 263.f,  263.f },
  { -36.f,  -80.f,   51.f,   95.f },
  { -80.f,  -168.f,  95.f,  183.f },
  { -168.f, -344.f, 183.f,  359.f },
};

// Replica of XLA:CPU GenerateVF32Exp (Cephes/Eigen expf), UNFUSED mul/add.
__device__ __forceinline__ float pexpf(float xin) {
#pragma clang fp contract(off)
  const float exp_hi = 88.3762626647950f;
  const float exp_lo = -88.3762626647949f;
  const float LOG2EF = 1.44269504088896341f;
  const float C1 = 0.693359375f;
  const float C2 = -2.12194440e-4f;
  const float p0 = 1.9875691500E-4f;
  const float p1 = 1.3981999507E-3f;
  const float p2 = 8.3334519073E-3f;
  const float p3 = 4.1665795894E-2f;
  const float p4 = 1.6666665459E-1f;
  const float p5 = 5.0000001201E-1f;
  float x = fminf(fmaxf(xin, exp_lo), exp_hi);
  float fx = floorf(x * LOG2EF + 0.5f);
  float tmp = C1 * fx;
  float z = C2 * fx;
  x = x - tmp;
  x = x - z;
  z = x * x;
  float y = x * p0 + p1;
  y = y * x + p2;
  y = y * x + p3;
  y = y * x + p4;
  y = y * x + p5;
  y = y * z + x;
  y = 1.0f + y;
  int n = (int)fx;
  u32 e = ((u32)(n + 127)) << 23;
  return y * __uint_as_float(e);
}

__device__ __forceinline__ void decode_box(const float* __restrict__ bbox, int aidx,
                                           float4* ob, float* oarea, bool* okeep) {
#pragma clang fp contract(off)
  int pos = aidx / 9;
  int a = aidx - pos * 9;
  int w = pos & 511;
  int h = pos >> 9;
  float shx = (float)(w * 8);
  float shy = (float)(h * 8);
  float ax1 = c_anch[a][0] + shx;
  float ay1 = c_anch[a][1] + shy;
  float ax2 = c_anch[a][2] + shx;
  float ay2 = c_anch[a][3] + shy;
  float aw = (ax2 - ax1) + 1.0f;
  float ah = (ay2 - ay1) + 1.0f;
  float acx = ax1 + 0.5f * aw;
  float acy = ay1 + 0.5f * ah;
  const float* d = bbox + (size_t)pos * 36 + (size_t)a * 4;
  float dx = d[0], dy = d[1], dw = d[2], dh = d[3];
  float pcx = dx * aw + acx;
  float pcy = dy * ah + acy;
  float pw = pexpf(dw) * aw;
  float ph = pexpf(dh) * ah;
  float x1 = pcx - 0.5f * pw;
  float y1 = pcy - 0.5f * ph;
  float x2 = pcx + 0.5f * pw;
  float y2 = pcy + 0.5f * ph;
  x1 = fminf(fmaxf(x1, 0.0f), 4095.0f);
  y1 = fminf(fmaxf(y1, 0.0f), 4095.0f);
  x2 = fminf(fmaxf(x2, 0.0f), 4095.0f);
  y2 = fminf(fmaxf(y2, 0.0f), 4095.0f);
  *ob = make_float4(x1, y1, x2, y2);
  float ww = (x2 - x1) + 1.0f;
  float hh = (y2 - y1) + 1.0f;
  *oarea = ww * hh;
  *okeep = (ww >= 16.0f) && (hh >= 16.0f);
}

// Stage A (init of ctl/hist fused into block 0).
__global__ void k_scores(const float* __restrict__ cls, const float* __restrict__ bbox,
                         u32* __restrict__ keys, u32* __restrict__ ctl,
                         u32* __restrict__ hist) {
#pragma clang fp contract(off)
  int t = blockIdx.x * blockDim.x + threadIdx.x;
  if (blockIdx.x == 0) {
    if (threadIdx.x < 16) ctl[threadIdx.x] = (threadIdx.x == 1) ? (u32)K_PRE : 0u;
    hist[threadIdx.x] = 0u;
  }
  if (t >= N_ANCH) return;
  int pos = t / 9;
  int a = t - pos * 9;
  float s0 = cls[(size_t)pos * 18 + a];
  float s1 = cls[(size_t)pos * 18 + 9 + a];
  float m = fmaxf(s0, s1);
  float e0 = pexpf(s0 - m);
  float e1 = pexpf(s1 - m);
  float p = e1 / (e0 + e1);
  float4 box; float area; bool km;
  decode_box(bbox, t, &box, &area, &km);
  keys[t] = km ? (__float_as_uint(p) | 0x80000000u) : 0u;
}

// Histogram pass + fused last-block scan (device-scope last-block pattern).
__global__ void k_histscan(const u32* __restrict__ keys, u32* __restrict__ ctl,
                           u32* __restrict__ hist, int shift, int pass) {
  __shared__ u32 lh[256];
  __shared__ u32 s_last;
  int t = threadIdx.x;
  lh[t] = 0u;
  __syncthreads();
  u32 prefix = ctl[0];
  u32 msk = (shift == 24) ? 0u : (0xFFFFFFFFu << (shift + 8));
  int stride = gridDim.x * blockDim.x;
  for (int i = blockIdx.x * blockDim.x + t; i < N_ANCH; i += stride) {
    u32 k = keys[i];
    if ((k & msk) == prefix) atomicAdd(&lh[(k >> shift) & 0xFFu], 1u);
  }
  __syncthreads();
  if (lh[t]) atomicAdd(&hist[t], lh[t]);
  __syncthreads();
  if (t == 0) {
    __threadfence();
    u32 old = atomicAdd(&ctl[8 + pass], 1u);
    s_last = (old == gridDim.x - 1) ? 1u : 0u;
  }
  __syncthreads();
  if (!s_last) return;
  __threadfence();
  __shared__ u32 sh[256];
  __shared__ u32 horig[256];
  __shared__ int s_d;
  u32 h = atomicAdd(&hist[t], 0u);   // coherent read (bypass stale L1)
  sh[t] = h; horig[t] = h;
  if (t == 0) s_d = 0;
  u32 krem = ctl[1];
  __syncthreads();
  u32 v = h;
  for (int off = 1; off < 256; off <<= 1) {
    u32 add = (t + off < 256) ? sh[t + off] : 0u;
    __syncthreads();
    v += add;
    sh[t] = v;
    __syncthreads();
  }
  if (sh[t] >= krem) atomicMax(&s_d, t);
  __syncthreads();
  if (t == 0) {
    int d = s_d;
    u32 cum = sh[d] - horig[d];
    ctl[0] |= ((u32)d) << shift;
    ctl[1] = krem - cum;
    if (shift == 0) { ctl[2] = ctl[0]; ctl[3] = ctl[1]; }
  }
  hist[t] = 0u;
}

// Collect winners: per-block LDS staging, ONE global atomic per block.
// (R5's 12000 serialized one-address atomics were ~hundreds of µs.)
// sel/comps order is arbitrary — rankdec sorts by comps, so output is
// deterministic regardless of staging order.
__global__ void k_collect(const u32* __restrict__ keys, u32* __restrict__ ctl,
                          int* __restrict__ sel, int* __restrict__ tie,
                          u64* __restrict__ comps) {
  __shared__ int stI[2048];
  __shared__ u64 stC[2048];
  __shared__ int stT[256];
  __shared__ u32 s_cnt, s_tcnt, s_base, s_tbase;
  int tid = threadIdx.x;
  if (tid == 0) { s_cnt = 0; s_tcnt = 0; }
  __syncthreads();
  u32 kstar = ctl[2];
  int stride = gridDim.x * blockDim.x;
  for (int i = blockIdx.x * blockDim.x + tid; i < N_ANCH; i += stride) {
    u32 k = keys[i];
    if (k > kstar) {
      u32 p = atomicAdd(&s_cnt, 1u);
      u64 cmp = ((u64)k << 32) | (u64)(0xFFFFFFFFu - (u32)i);
      if (p < 2048u) { stI[p] = i; stC[p] = cmp; }
      else { u32 g = atomicAdd(&ctl[4], 1u); sel[g] = i; comps[g] = cmp; }
    } else if (k == kstar) {
      u32 p = atomicAdd(&s_tcnt, 1u);
      if (p < 256u) stT[p] = i;
      else { u32 g = atomicAdd(&ctl[5], 1u); if (g < TIE_CAP) tie[g] = i; }
    }
  }
  __syncthreads();
  if (tid == 0) {
    u32 n = min(s_cnt, 2048u);
    s_base = atomicAdd(&ctl[4], n);
    u32 tn = min(s_tcnt, 256u);
    s_tbase = atomicAdd(&ctl[5], tn);
  }
  __syncthreads();
  u32 n = min(s_cnt, 2048u);
  for (u32 q = tid; q < n; q += blockDim.x) {
    sel[s_base + q] = stI[q];
    comps[s_base + q] = stC[q];
  }
  u32 tn = min(s_tcnt, 256u);
  for (u32 q = tid; q < tn; q += blockDim.x) {
    u32 g = s_tbase + q;
    if (g < TIE_CAP) tie[g] = stT[q];
  }
}

__global__ void k_tiepick(const u32* __restrict__ ctl, const int* __restrict__ tie,
                          int* __restrict__ sel, u64* __restrict__ comps) {
  u32 T = ctl[5]; if (T > TIE_CAP) T = TIE_CAP;
  if (T > 8192u) T = 8192u;
  u32 need = ctl[3];
  u32 base = ctl[4];
  u32 kstar = ctl[2];
  for (u32 t = threadIdx.x; t < T; t += blockDim.x) {
    int v = tie[t];
    u32 r = 0;
    for (u32 u = 0; u < T; ++u) r += (tie[u] < v) ? 1u : 0u;
    if (r < need) {
      sel[base + r] = v;
      comps[base + r] = ((u64)kstar << 32) | (u64)(0xFFFFFFFFu - (u32)v);
    }
  }
}

// Rank sort: one wave per 8 candidates; coalesced L2-resident j-scan.
__global__ void k_rankdec(const u64* __restrict__ comps, const int* __restrict__ sel,
                          const float* __restrict__ bbox,
                          float4* __restrict__ props, float* __restrict__ areas) {
  int lane = threadIdx.x & 63;
  int wave = threadIdx.x >> 6;
  int base = (blockIdx.x * 4 + wave) * 8;
  u64 c0 = comps[base + 0], c1 = comps[base + 1], c2 = comps[base + 2], c3 = comps[base + 3];
  u64 c4 = comps[base + 4], c5 = comps[base + 5], c6 = comps[base + 6], c7 = comps[base + 7];
  int n0 = 0, n1 = 0, n2 = 0, n3 = 0, n4 = 0, n5 = 0, n6 = 0, n7 = 0;
#pragma unroll 4
  for (int j = lane; j < K_PRE; j += 64) {
    u64 v = comps[j];
    n0 += (v > c0); n1 += (v > c1); n2 += (v > c2); n3 += (v > c3);
    n4 += (v > c4); n5 += (v > c5); n6 += (v > c6); n7 += (v > c7);
  }
  for (int off = 32; off; off >>= 1) {
    n0 += __shfl_xor(n0, off); n1 += __shfl_xor(n1, off);
    n2 += __shfl_xor(n2, off); n3 += __shfl_xor(n3, off);
    n4 += __shfl_xor(n4, off); n5 += __shfl_xor(n5, off);
    n6 += __shfl_xor(n6, off); n7 += __shfl_xor(n7, off);
  }
  int rk = n0;
  rk = (lane == 1) ? n1 : rk; rk = (lane == 2) ? n2 : rk;
  rk = (lane == 3) ? n3 : rk; rk = (lane == 4) ? n4 : rk;
  rk = (lane == 5) ? n5 : rk; rk = (lane == 6) ? n6 : rk;
  rk = (lane == 7) ? n7 : rk;
  if (lane < 8) {
    float4 box; float area; bool km;
    decode_box(bbox, sel[base + lane], &box, &area, &km);
    props[rk] = box;
    areas[rk] = area;
  }
}

// IoU bitmask. Only three regions are ever read by k_nms:
//   y >= x+2 : far-OR rows             -> mask[i][y]
//   y == x   : decision diagonal block -> diagbuf[x][lane]   (contiguous!)
//   y == x-1 : subdiag (IoU-symmetry keeps(c)->word c+1)
//                                      -> subbuf[x][lane]    (contiguous!)
__global__ void k_mask(const float4* __restrict__ props, const float* __restrict__ areas,
                       u64* __restrict__ mask, u64* __restrict__ diagbuf,
                       u64* __restrict__ subbuf) {
#pragma clang fp contract(off)
  int x = blockIdx.x, y = blockIdx.y;
  if (y + 1 < x || y == x + 1) return;
  __shared__ float4 bj[64];
  __shared__ float aj[64];
  int j0 = y * 64;
  bj[threadIdx.x] = props[j0 + threadIdx.x];
  aj[threadIdx.x] = areas[j0 + threadIdx.x];
  __syncthreads();
  int i = x * 64 + threadIdx.x;
  float4 bi = props[i];
  float ai = areas[i];
  u64 bits = 0;
  for (int jj = 0; jj < 64; ++jj) {
    int j = j0 + jj;
    float4 bb = bj[jj];
    float xx1 = fmaxf(bi.x, bb.x);
    float yy1 = fmaxf(bi.y, bb.y);
    float xx2 = fminf(bi.z, bb.z);
    float yy2 = fminf(bi.w, bb.w);
    float w = fmaxf(0.0f, (xx2 - xx1) + 1.0f);
    float h = fmaxf(0.0f, (yy2 - yy1) + 1.0f);
    float inter = w * h;
    float iou = inter / ((ai + aj[jj]) - inter);
    if ((iou > 0.7f) && (j < K_PRE)) bits |= (1ull << jj);
  }
  if (y == x)          diagbuf[x * 64 + threadIdx.x] = bits;
  else if (y == x - 1) subbuf[x * 64 + threadIdx.x] = bits;
  else                 mask[(size_t)i * NWORD + y] = bits;
}

// Barrier without vmcnt drain: cross-wave comms are LDS-only (lgkmcnt covers
// ds ops incl. atomics); global loads are consumed by their own wave.
#define NMS_BAR() asm volatile("s_waitcnt lgkmcnt(0)\n\ts_barrier" ::: "memory")

// Blocked greedy NMS v6 (1024 threads, 16 waves, one barrier per chunk):
//  - wave0: decision via diagbuf (coalesced, prefetched 1 chunk ahead) with
//    ballot suppression; then keeps(c)->word c+1 via subbuf ballot (IoU
//    symmetry); publish kept list.
//  - waves 1..15: during chunk c, OR keeps(c-1) rows into all words >= c+1.
//    Work unit = (row, 64-word segment): one coalesced 512B row load + LDS
//    atomicOr. ~2-3 independent loads/wave/chunk, a full chunk to land.
//    Deadline check: word w needs keeps(w-1) [subbuf, in chunk w-1] and
//    keeps(<=w-2) [far, during chunks <= w-1] before decision(w). OK.
__global__ void __launch_bounds__(1024) k_nms(const u64* __restrict__ mask,
                                              const u64* __restrict__ diagbuf,
                                              const u64* __restrict__ subbuf,
                                              const float4* __restrict__ props,
                                              float* __restrict__ out) {
  __shared__ u64 rem[NWORD];
  __shared__ int keepb[K_POST];
  __shared__ int kept[2][64];
  __shared__ int s_kk[2];
  __shared__ int s_nk;
  __shared__ int s_brk;
  int tid = threadIdx.x;
  int lane = tid & 63;
  int wave = tid >> 6;
  for (int w = tid; w < NWORD; w += 1024) {
    int base = w * 64;
    u64 v;
    if (base + 64 <= K_PRE) v = 0ull;
    else if (base >= K_PRE) v = ~0ull;
    else v = (~0ull) << (K_PRE - base);
    rem[w] = v;
  }
  if (tid == 0) { s_nk = 0; s_brk = 0; s_kk[0] = 0; s_kk[1] = 0; }
  __syncthreads();

  u64 diagA = 0, diagB = 0, subA = 0, subB = 0;
  if (wave == 0) {
    diagA = diagbuf[lane];        // chunk 0 diagonal
    subA  = subbuf[64 + lane];    // rows of chunk 1 at word 0
  }
  int nk = 0;

  for (int c = 0; c < NWORD; ++c) {
    if (s_brk) break;
    if (wave == 0) {
      if (c + 1 < NWORD) diagB = diagbuf[(c + 1) * 64 + lane];
      subB = (c + 2 < NWORD) ? subbuf[(c + 2) * 64 + lane] : 0ull;
      // decision for chunk c
      u64 w = ~rem[c];
      u64 myrow = diagA;
      int kk = 0;
      u64 km = 0;
      while (w != 0ull && nk < K_POST) {
        int j = (int)__builtin_ctzll(w);
        if (lane == 0) { keepb[nk] = (c << 6) | j; kept[c & 1][kk] = (c << 6) | j; }
        km |= (1ull << j);
        nk++; kk++;
        u64 sup = __ballot((int)((myrow >> j) & 1ull));
        w &= ~sup;
        w &= ~(1ull << j);
      }
      // keeps(c) -> word c+1: subA[lane] = row(64(c+1)+lane) word c;
      // lane suppressed iff it overlaps any kept row of chunk c.
      if (c + 1 < NWORD) {
        u64 v = __ballot((int)((subA & km) != 0ull));
        if (lane == 0 && v) atomicOr((unsigned long long*)&rem[c + 1], (unsigned long long)v);
      }
      if (lane == 0) {
        s_kk[c & 1] = kk;
        s_nk = nk;
        if (nk >= K_POST) s_brk = 1;
      }
      diagA = diagB; subA = subB;
    } else if (c >= 1) {
      // far OR: keeps(c-1) -> words [c+1, NWORD)
      int kkp = s_kk[(c - 1) & 1];
      int wv = wave - 1;  // 0..14
      for (int unit = wv; unit < kkp * 3; unit += 15) {
        int q = unit / 3;
        int s = unit - q * 3;
        int w = c + 1 + s * 64 + lane;
        if (w < NWORD) {
          u64 bits = mask[(size_t)kept[(c - 1) & 1][q] * NWORD + w];
          if (bits) atomicOr((unsigned long long*)&rem[w], (unsigned long long)bits);
        }
      }
    }
    NMS_BAR();
  }
  __syncthreads();
  int fnk = s_nk;
  for (int t = tid; t < K_POST; t += 1024) {
    int kidx = (t < fnk) ? keepb[t] : 0;   // exhausted: argmax over -inf -> 0
    float4 b = props[kidx];
    out[t * 5 + 0] = 0.0f;
    out[t * 5 + 1] = b.x;
    out[t * 5 + 2] = b.y;
    out[t * 5 + 3] = b.z;
    out[t * 5 + 4] = b.w;
  }
}

extern "C" void kernel_launch(void* const* d_in, const int* in_sizes, int n_in,
                              void* d_out, int out_size, void* d_ws, size_t ws_size,
                              hipStream_t stream) {
  const float* cls  = (const float*)d_in[0];
  const float* bbox = (const float*)d_in[1];
  float* out = (float*)d_out;
  char* ws = (char*)d_ws;

  // Layout. mask [0,18096128) overlays keys/ctl/hist/sel/tie (all dead before
  // k_mask). comps/props/areas/diagbuf/subbuf live beyond 18096128.
  u64* mask    = (u64*)ws;                      // u64[12032*188]
  u32* keys    = (u32*)ws;                      // [0, 9437184)
  u32* ctl     = (u32*)(ws + 9437184);
  u32* hist    = (u32*)(ws + 9437248);
  int* sel     = (int*)(ws + 9438464);
  int* tie     = (int*)(ws + 9486592);
  u64* comps   = (u64*)(ws + 18096128);         // +96256
  float4* props= (float4*)(ws + 18240512);      // +192512
  float* areas = (float*)(ws + 18433024);       // +48128
  u64* diagbuf = (u64*)(ws + 18481152);         // +96256
  u64* subbuf  = (u64*)(ws + 18577408);         // +96256 -> 18673664 total

  k_scores<<<dim3((N_ANCH + 255) / 256), dim3(256), 0, stream>>>(cls, bbox, keys, ctl, hist);
  const int shifts[4] = {24, 16, 8, 0};
  for (int s = 0; s < 4; ++s)
    k_histscan<<<dim3(256), dim3(256), 0, stream>>>(keys, ctl, hist, shifts[s], s);
  k_collect<<<dim3(256), dim3(256), 0, stream>>>(keys, ctl, sel, tie, comps);
  k_tiepick<<<dim3(1), dim3(256), 0, stream>>>(ctl, tie, sel, comps);
  k_rankdec<<<dim3(375), dim3(256), 0, stream>>>(comps, sel, bbox, props, areas);
  k_mask<<<dim3(188, 188), dim3(64), 0, stream>>>(props, areas, mask, diagbuf, subbuf);
  k_nms<<<dim3(1), dim3(1024), 0, stream>>>(mask, diagbuf, subbuf, props, out);
}

// Round 7
// 365.321 us; speedup vs baseline: 1.8947x; 1.0208x over previous
//
#include <hip/hip_runtime.h>
#include <cstdint>
#include <cstddef>

#pragma clang fp contract(off)

#define N_ANCH 2359296
#define K_PRE  12000
#define K_POST 2000
#define NWORD  188
#define TIE_CAP 65536

typedef unsigned int u32;
typedef unsigned long long u64;

__constant__ float c_anch[9][4] = {
  { -84.f,  -40.f,   99.f,   55.f },
  { -176.f, -88.f,  191.f,  103.f },
  { -360.f, -184.f, 375.f,  199.f },
  { -56.f,  -56.f,   71.f,   71.f },
  { -120.f, -120.f, 135.f,  135.f },
  { -248.f, -248.f, 263.f,  263.f },
  { -36.f,  -80.f,   51.f,   95.f },
  { -80.f,  -168.f,  95.f,  183.f },
  { -168.f, -344.f, 183.f,  359.f },
};

// Replica of XLA:CPU GenerateVF32Exp (Cephes/Eigen expf), UNFUSED mul/add.
__device__ __forceinline__ float pexpf(float xin) {
#pragma clang fp contract(off)
  const float exp_hi = 88.3762626647950f;
  const float exp_lo = -88.3762626647949f;
  const float LOG2EF = 1.44269504088896341f;
  const float C1 = 0.693359375f;
  const float C2 = -2.12194440e-4f;
  const float p0 = 1.9875691500E-4f;
  const float p1 = 1.3981999507E-3f;
  const float p2 = 8.3334519073E-3f;
  const float p3 = 4.1665795894E-2f;
  const float p4 = 1.6666665459E-1f;
  const float p5 = 5.0000001201E-1f;
  float x = fminf(fmaxf(xin, exp_lo), exp_hi);
  float fx = floorf(x * LOG2EF + 0.5f);
  float tmp = C1 * fx;
  float z = C2 * fx;
  x = x - tmp;
  x = x - z;
  z = x * x;
  float y = x * p0 + p1;
  y = y * x + p2;
  y = y * x + p3;
  y = y * x + p4;
  y = y * x + p5;
  y = y * z + x;
  y = 1.0f + y;
  int n = (int)fx;
  u32 e = ((u32)(n + 127)) << 23;
  return y * __uint_as_float(e);
}

__device__ __forceinline__ void decode_box(const float* __restrict__ bbox, int aidx,
                                           float4* ob, float* oarea, bool* okeep) {
#pragma clang fp contract(off)
  int pos = aidx / 9;
  int a = aidx - pos * 9;
  int w = pos & 511;
  int h = pos >> 9;
  float shx = (float)(w * 8);
  float shy = (float)(h * 8);
  float ax1 = c_anch[a][0] + shx;
  float ay1 = c_anch[a][1] + shy;
  float ax2 = c_anch[a][2] + shx;
  float ay2 = c_anch[a][3] + shy;
  float aw = (ax2 - ax1) + 1.0f;
  float ah = (ay2 - ay1) + 1.0f;
  float acx = ax1 + 0.5f * aw;
  float acy = ay1 + 0.5f * ah;
  const float* d = bbox + (size_t)pos * 36 + (size_t)a * 4;
  float dx = d[0], dy = d[1], dw = d[2], dh = d[3];
  float pcx = dx * aw + acx;
  float pcy = dy * ah + acy;
  float pw = pexpf(dw) * aw;
  float ph = pexpf(dh) * ah;
  float x1 = pcx - 0.5f * pw;
  float y1 = pcy - 0.5f * ph;
  float x2 = pcx + 0.5f * pw;
  float y2 = pcy + 0.5f * ph;
  x1 = fminf(fmaxf(x1, 0.0f), 4095.0f);
  y1 = fminf(fmaxf(y1, 0.0f), 4095.0f);
  x2 = fminf(fmaxf(x2, 0.0f), 4095.0f);
  y2 = fminf(fmaxf(y2, 0.0f), 4095.0f);
  *ob = make_float4(x1, y1, x2, y2);
  float ww = (x2 - x1) + 1.0f;
  float hh = (y2 - y1) + 1.0f;
  *oarea = ww * hh;
  *okeep = (ww >= 16.0f) && (hh >= 16.0f);
}

// Stage A (init of ctl/hist fused into block 0).
__global__ void k_scores(const float* __restrict__ cls, const float* __restrict__ bbox,
                         u32* __restrict__ keys, u32* __restrict__ ctl,
                         u32* __restrict__ hist) {
#pragma clang fp contract(off)
  int t = blockIdx.x * blockDim.x + threadIdx.x;
  if (blockIdx.x == 0) {
    if (threadIdx.x < 16) ctl[threadIdx.x] = (threadIdx.x == 1) ? (u32)K_PRE : 0u;
    hist[threadIdx.x] = 0u;
  }
  if (t >= N_ANCH) return;
  int pos = t / 9;
  int a = t - pos * 9;
  float s0 = cls[(size_t)pos * 18 + a];
  float s1 = cls[(size_t)pos * 18 + 9 + a];
  float m = fmaxf(s0, s1);
  float e0 = pexpf(s0 - m);
  float e1 = pexpf(s1 - m);
  float p = e1 / (e0 + e1);
  float4 box; float area; bool km;
  decode_box(bbox, t, &box, &area, &km);
  keys[t] = km ? (__float_as_uint(p) | 0x80000000u) : 0u;
}

// Histogram pass + fused last-block scan (device-scope last-block pattern).
__global__ void k_histscan(const u32* __restrict__ keys, u32* __restrict__ ctl,
                           u32* __restrict__ hist, int shift, int pass) {
  __shared__ u32 lh[256];
  __shared__ u32 s_last;
  int t = threadIdx.x;
  lh[t] = 0u;
  __syncthreads();
  u32 prefix = ctl[0];
  u32 msk = (shift == 24) ? 0u : (0xFFFFFFFFu << (shift + 8));
  int stride = gridDim.x * blockDim.x;
  for (int i = blockIdx.x * blockDim.x + t; i < N_ANCH; i += stride) {
    u32 k = keys[i];
    if ((k & msk) == prefix) atomicAdd(&lh[(k >> shift) & 0xFFu], 1u);
  }
  __syncthreads();
  if (lh[t]) atomicAdd(&hist[t], lh[t]);
  __syncthreads();
  if (t == 0) {
    __threadfence();
    u32 old = atomicAdd(&ctl[8 + pass], 1u);
    s_last = (old == gridDim.x - 1) ? 1u : 0u;
  }
  __syncthreads();
  if (!s_last) return;
  __threadfence();
  __shared__ u32 sh[256];
  __shared__ u32 horig[256];
  __shared__ int s_d;
  u32 h = atomicAdd(&hist[t], 0u);   // coherent read (bypass stale L1)
  sh[t] = h; horig[t] = h;
  if (t == 0) s_d = 0;
  u32 krem = ctl[1];
  __syncthreads();
  u32 v = h;
  for (int off = 1; off < 256; off <<= 1) {
    u32 add = (t + off < 256) ? sh[t + off] : 0u;
    __syncthreads();
    v += add;
    sh[t] = v;
    __syncthreads();
  }
  if (sh[t] >= krem) atomicMax(&s_d, t);
  __syncthreads();
  if (t == 0) {
    int d = s_d;
    u32 cum = sh[d] - horig[d];
    ctl[0] |= ((u32)d) << shift;
    ctl[1] = krem - cum;
    if (shift == 0) { ctl[2] = ctl[0]; ctl[3] = ctl[1]; }
  }
  hist[t] = 0u;
}

// Collect winners: per-block LDS staging, ONE global atomic per block.
__global__ void k_collect(const u32* __restrict__ keys, u32* __restrict__ ctl,
                          int* __restrict__ sel, int* __restrict__ tie,
                          u64* __restrict__ comps) {
  __shared__ int stI[2048];
  __shared__ u64 stC[2048];
  __shared__ int stT[256];
  __shared__ u32 s_cnt, s_tcnt, s_base, s_tbase;
  int tid = threadIdx.x;
  if (tid == 0) { s_cnt = 0; s_tcnt = 0; }
  __syncthreads();
  u32 kstar = ctl[2];
  int stride = gridDim.x * blockDim.x;
  for (int i = blockIdx.x * blockDim.x + tid; i < N_ANCH; i += stride) {
    u32 k = keys[i];
    if (k > kstar) {
      u32 p = atomicAdd(&s_cnt, 1u);
      u64 cmp = ((u64)k << 32) | (u64)(0xFFFFFFFFu - (u32)i);
      if (p < 2048u) { stI[p] = i; stC[p] = cmp; }
      else { u32 g = atomicAdd(&ctl[4], 1u); sel[g] = i; comps[g] = cmp; }
    } else if (k == kstar) {
      u32 p = atomicAdd(&s_tcnt, 1u);
      if (p < 256u) stT[p] = i;
      else { u32 g = atomicAdd(&ctl[5], 1u); if (g < TIE_CAP) tie[g] = i; }
    }
  }
  __syncthreads();
  if (tid == 0) {
    u32 n = min(s_cnt, 2048u);
    s_base = atomicAdd(&ctl[4], n);
    u32 tn = min(s_tcnt, 256u);
    s_tbase = atomicAdd(&ctl[5], tn);
  }
  __syncthreads();
  u32 n = min(s_cnt, 2048u);
  for (u32 q = tid; q < n; q += blockDim.x) {
    sel[s_base + q] = stI[q];
    comps[s_base + q] = stC[q];
  }
  u32 tn = min(s_tcnt, 256u);
  for (u32 q = tid; q < tn; q += blockDim.x) {
    u32 g = s_tbase + q;
    if (g < TIE_CAP) tie[g] = stT[q];
  }
}

__global__ void k_tiepick(const u32* __restrict__ ctl, const int* __restrict__ tie,
                          int* __restrict__ sel, u64* __restrict__ comps) {
  u32 T = ctl[5]; if (T > TIE_CAP) T = TIE_CAP;
  if (T > 8192u) T = 8192u;
  u32 need = ctl[3];
  u32 base = ctl[4];
  u32 kstar = ctl[2];
  for (u32 t = threadIdx.x; t < T; t += blockDim.x) {
    int v = tie[t];
    u32 r = 0;
    for (u32 u = 0; u < T; ++u) r += (tie[u] < v) ? 1u : 0u;
    if (r < need) {
      sel[base + r] = v;
      comps[base + r] = ((u64)kstar << 32) | (u64)(0xFFFFFFFFu - (u32)v);
    }
  }
}

// Rank sort: one wave per 8 candidates; coalesced L2-resident j-scan.
__global__ void k_rankdec(const u64* __restrict__ comps, const int* __restrict__ sel,
                          const float* __restrict__ bbox,
                          float4* __restrict__ props, float* __restrict__ areas) {
  int lane = threadIdx.x & 63;
  int wave = threadIdx.x >> 6;
  int base = (blockIdx.x * 4 + wave) * 8;
  u64 c0 = comps[base + 0], c1 = comps[base + 1], c2 = comps[base + 2], c3 = comps[base + 3];
  u64 c4 = comps[base + 4], c5 = comps[base + 5], c6 = comps[base + 6], c7 = comps[base + 7];
  int n0 = 0, n1 = 0, n2 = 0, n3 = 0, n4 = 0, n5 = 0, n6 = 0, n7 = 0;
#pragma unroll 4
  for (int j = lane; j < K_PRE; j += 64) {
    u64 v = comps[j];
    n0 += (v > c0); n1 += (v > c1); n2 += (v > c2); n3 += (v > c3);
    n4 += (v > c4); n5 += (v > c5); n6 += (v > c6); n7 += (v > c7);
  }
  for (int off = 32; off; off >>= 1) {
    n0 += __shfl_xor(n0, off); n1 += __shfl_xor(n1, off);
    n2 += __shfl_xor(n2, off); n3 += __shfl_xor(n3, off);
    n4 += __shfl_xor(n4, off); n5 += __shfl_xor(n5, off);
    n6 += __shfl_xor(n6, off); n7 += __shfl_xor(n7, off);
  }
  int rk = n0;
  rk = (lane == 1) ? n1 : rk; rk = (lane == 2) ? n2 : rk;
  rk = (lane == 3) ? n3 : rk; rk = (lane == 4) ? n4 : rk;
  rk = (lane == 5) ? n5 : rk; rk = (lane == 6) ? n6 : rk;
  rk = (lane == 7) ? n7 : rk;
  if (lane < 8) {
    float4 box; float area; bool km;
    decode_box(bbox, sel[base + lane], &box, &area, &km);
    props[rk] = box;
    areas[rk] = area;
  }
}

// IoU bitmask. Only three regions are ever read by k_nms:
//   y >= x+2 : far-OR rows             -> mask[i][y]
//   y == x   : decision diagonal block -> diagbuf[x][lane]   (contiguous!)
//   y == x-1 : subdiag (IoU-symmetry keeps(c)->word c+1)
//                                      -> subbuf[x][lane]    (contiguous!)
__global__ void k_mask(const float4* __restrict__ props, const float* __restrict__ areas,
                       u64* __restrict__ mask, u64* __restrict__ diagbuf,
                       u64* __restrict__ subbuf) {
#pragma clang fp contract(off)
  int x = blockIdx.x, y = blockIdx.y;
  if (y + 1 < x || y == x + 1) return;
  __shared__ float4 bj[64];
  __shared__ float aj[64];
  int j0 = y * 64;
  bj[threadIdx.x] = props[j0 + threadIdx.x];
  aj[threadIdx.x] = areas[j0 + threadIdx.x];
  __syncthreads();
  int i = x * 64 + threadIdx.x;
  float4 bi = props[i];
  float ai = areas[i];
  u64 bits = 0;
  for (int jj = 0; jj < 64; ++jj) {
    int j = j0 + jj;
    float4 bb = bj[jj];
    float xx1 = fmaxf(bi.x, bb.x);
    float yy1 = fmaxf(bi.y, bb.y);
    float xx2 = fminf(bi.z, bb.z);
    float yy2 = fminf(bi.w, bb.w);
    float w = fmaxf(0.0f, (xx2 - xx1) + 1.0f);
    float h = fmaxf(0.0f, (yy2 - yy1) + 1.0f);
    float inter = w * h;
    float iou = inter / ((ai + aj[jj]) - inter);
    if ((iou > 0.7f) && (j < K_PRE)) bits |= (1ull << jj);
  }
  if (y == x)          diagbuf[x * 64 + threadIdx.x] = bits;
  else if (y == x - 1) subbuf[x * 64 + threadIdx.x] = bits;
  else                 mask[(size_t)i * NWORD + y] = bits;
}

// Barrier without vmcnt drain: cross-wave comms are LDS-only (lgkmcnt covers
// ds ops incl. atomics); global loads are consumed by their own wave.
#define NMS_BAR() asm volatile("s_waitcnt lgkmcnt(0)\n\ts_barrier" ::: "memory")

// Blocked greedy NMS v7 (1024 threads, 16 waves, one barrier per chunk):
//  - wave0: decision via diagbuf (coalesced, prefetched 1 chunk ahead) with
//    ballot suppression; then keeps(c)->word c+1 via subbuf ballot (IoU
//    symmetry); publish kept list.
//  - waves 1..15: during chunk c, OR keeps(c-1) rows into all words >= c+1.
//    v7 change: BATCH-ISSUE up to 4 independent row loads into named regs,
//    then do the LDS atomicOrs — one ~900cy HBM latency per chunk instead of
//    2-3 serialized load->atomicOr chains (R6's 2470cy/chunk -> ~1150).
__global__ void __launch_bounds__(1024) k_nms(const u64* __restrict__ mask,
                                              const u64* __restrict__ diagbuf,
                                              const u64* __restrict__ subbuf,
                                              const float4* __restrict__ props,
                                              float* __restrict__ out) {
  __shared__ u64 rem[NWORD];
  __shared__ int keepb[K_POST];
  __shared__ int kept[2][64];
  __shared__ int s_kk[2];
  __shared__ int s_nk;
  __shared__ int s_brk;
  int tid = threadIdx.x;
  int lane = tid & 63;
  int wave = tid >> 6;
  for (int w = tid; w < NWORD; w += 1024) {
    int base = w * 64;
    u64 v;
    if (base + 64 <= K_PRE) v = 0ull;
    else if (base >= K_PRE) v = ~0ull;
    else v = (~0ull) << (K_PRE - base);
    rem[w] = v;
  }
  if (tid == 0) { s_nk = 0; s_brk = 0; s_kk[0] = 0; s_kk[1] = 0; }
  __syncthreads();

  u64 diagA = 0, diagB = 0, subA = 0, subB = 0;
  if (wave == 0) {
    diagA = diagbuf[lane];        // chunk 0 diagonal
    subA  = subbuf[64 + lane];    // rows of chunk 1 at word 0
  }
  int nk = 0;

  for (int c = 0; c < NWORD; ++c) {
    if (s_brk) break;
    if (wave == 0) {
      if (c + 1 < NWORD) diagB = diagbuf[(c + 1) * 64 + lane];
      subB = (c + 2 < NWORD) ? subbuf[(c + 2) * 64 + lane] : 0ull;
      // decision for chunk c
      u64 w = ~rem[c];
      u64 myrow = diagA;
      int kk = 0;
      u64 km = 0;
      while (w != 0ull && nk < K_POST) {
        int j = (int)__builtin_ctzll(w);
        if (lane == 0) { keepb[nk] = (c << 6) | j; kept[c & 1][kk] = (c << 6) | j; }
        km |= (1ull << j);
        nk++; kk++;
        u64 sup = __ballot((int)((myrow >> j) & 1ull));
        w &= ~sup;
        w &= ~(1ull << j);
      }
      // keeps(c) -> word c+1 via subbuf ballot (IoU symmetry)
      if (c + 1 < NWORD) {
        u64 v = __ballot((int)((subA & km) != 0ull));
        if (lane == 0 && v) atomicOr((unsigned long long*)&rem[c + 1], (unsigned long long)v);
      }
      if (lane == 0) {
        s_kk[c & 1] = kk;
        s_nk = nk;
        if (nk >= K_POST) s_brk = 1;
      }
      diagA = diagB; subA = subB;
    } else if (c >= 1) {
      // far OR: keeps(c-1) -> words [c+1, NWORD), batch-issued loads.
      int kkp = s_kk[(c - 1) & 1];
      const int* kb = &kept[(c - 1) & 1][0];
      int wv = wave - 1;           // 0..14
      int nu = kkp * 3;            // units: (row q, 64-word segment s)
      for (int b = wv; b < nu; b += 60) {
        int u0 = b, u1 = b + 15, u2 = b + 30, u3 = b + 45;
        u64 p0 = 0, p1 = 0, p2 = 0, p3 = 0;
        int w0 = 0, w1 = 0, w2 = 0, w3 = 0;
        if (u0 < nu) {
          int q = u0 / 3, s = u0 - q * 3;
          int w = c + 1 + s * 64 + lane;
          if (w < NWORD) { w0 = w; p0 = mask[(size_t)kb[q] * NWORD + w]; }
        }
        if (u1 < nu) {
          int q = u1 / 3, s = u1 - q * 3;
          int w = c + 1 + s * 64 + lane;
          if (w < NWORD) { w1 = w; p1 = mask[(size_t)kb[q] * NWORD + w]; }
        }
        if (u2 < nu) {
          int q = u2 / 3, s = u2 - q * 3;
          int w = c + 1 + s * 64 + lane;
          if (w < NWORD) { w2 = w; p2 = mask[(size_t)kb[q] * NWORD + w]; }
        }
        if (u3 < nu) {
          int q = u3 / 3, s = u3 - q * 3;
          int w = c + 1 + s * 64 + lane;
          if (w < NWORD) { w3 = w; p3 = mask[(size_t)kb[q] * NWORD + w]; }
        }
        if (p0) atomicOr((unsigned long long*)&rem[w0], (unsigned long long)p0);
        if (p1) atomicOr((unsigned long long*)&rem[w1], (unsigned long long)p1);
        if (p2) atomicOr((unsigned long long*)&rem[w2], (unsigned long long)p2);
        if (p3) atomicOr((unsigned long long*)&rem[w3], (unsigned long long)p3);
      }
    }
    NMS_BAR();
  }
  __syncthreads();
  int fnk = s_nk;
  for (int t = tid; t < K_POST; t += 1024) {
    int kidx = (t < fnk) ? keepb[t] : 0;   // exhausted: argmax over -inf -> 0
    float4 b = props[kidx];
    out[t * 5 + 0] = 0.0f;
    out[t * 5 + 1] = b.x;
    out[t * 5 + 2] = b.y;
    out[t * 5 + 3] = b.z;
    out[t * 5 + 4] = b.w;
  }
}

extern "C" void kernel_launch(void* const* d_in, const int* in_sizes, int n_in,
                              void* d_out, int out_size, void* d_ws, size_t ws_size,
                              hipStream_t stream) {
  const float* cls  = (const float*)d_in[0];
  const float* bbox = (const float*)d_in[1];
  float* out = (float*)d_out;
  char* ws = (char*)d_ws;

  // Layout. mask [0,18096128) overlays keys/ctl/hist/sel/tie (all dead before
  // k_mask). comps/props/areas/diagbuf/subbuf live beyond 18096128.
  u64* mask    = (u64*)ws;                      // u64[12032*188]
  u32* keys    = (u32*)ws;                      // [0, 9437184)
  u32* ctl     = (u32*)(ws + 9437184);
  u32* hist    = (u32*)(ws + 9437248);
  int* sel     = (int*)(ws + 9438464);
  int* tie     = (int*)(ws + 9486592);
  u64* comps   = (u64*)(ws + 18096128);         // +96256
  float4* props= (float4*)(ws + 18240512);      // +192512
  float* areas = (float*)(ws + 18433024);       // +48128
  u64* diagbuf = (u64*)(ws + 18481152);         // +96256
  u64* subbuf  = (u64*)(ws + 18577408);         // +96256 -> 18673664 total

  k_scores<<<dim3((N_ANCH + 255) / 256), dim3(256), 0, stream>>>(cls, bbox, keys, ctl, hist);
  const int shifts[4] = {24, 16, 8, 0};
  for (int s = 0; s < 4; ++s)
    k_histscan<<<dim3(256), dim3(256), 0, stream>>>(keys, ctl, hist, shifts[s], s);
  k_collect<<<dim3(256), dim3(256), 0, stream>>>(keys, ctl, sel, tie, comps);
  k_tiepick<<<dim3(1), dim3(256), 0, stream>>>(ctl, tie, sel, comps);
  k_rankdec<<<dim3(375), dim3(256), 0, stream>>>(comps, sel, bbox, props, areas);
  k_mask<<<dim3(188, 188), dim3(64), 0, stream>>>(props, areas, mask, diagbuf, subbuf);
  k_nms<<<dim3(1), dim3(1024), 0, stream>>>(mask, diagbuf, subbuf, props, out);
}